// Round 1
// baseline (705.063 us; speedup 1.0000x reference)
//
#include <hip/hip_runtime.h>
#include <hip/hip_bf16.h>
#include <stdint.h>

typedef unsigned short u16;
typedef unsigned int u32;
typedef short bf16x8 __attribute__((ext_vector_type(8)));
typedef float f32x4 __attribute__((ext_vector_type(4)));

#define SCALE_F 0.088388347648318447f   // 1/sqrt(128)
#define LAMBDA_INIT_F 0.2f
// B=2, T=1024, DIM=4096, H=32, Hk=8, D=128, NREP=4

__device__ __forceinline__ u16 f2bf(float f) {
  union { float f; u32 u; } v; v.f = f;
  u32 r = v.u + 0x7fffu + ((v.u >> 16) & 1u);   // RNE
  return (u16)(r >> 16);
}
__device__ __forceinline__ float bf2f(u16 u) {
  union { u32 u; float f; } v; v.u = ((u32)u) << 16;
  return v.f;
}

typedef __attribute__((address_space(1))) void gvoid_t;
typedef __attribute__((address_space(3))) void lvoid_t;
__device__ __forceinline__ void gload16(const void* g, void* l) {
  __builtin_amdgcn_global_load_lds((gvoid_t*)g, (lvoid_t*)l, 16, 0, 0);
}

// ---------------- elementwise cast f32 -> bf16 (vectorized) ----------------
__global__ void cast_f32_bf16(const float4* __restrict__ in, uint2* __restrict__ out, int n4) {
  int i = blockIdx.x * 256 + threadIdx.x;
  if (i >= n4) return;
  float4 v = in[i];
  uint2 o;
  o.x = (u32)f2bf(v.x) | ((u32)f2bf(v.y) << 16);
  o.y = (u32)f2bf(v.z) | ((u32)f2bf(v.w) << 16);
  out[i] = o;
}

// ------------- transpose+cast: w (K,N) f32  ->  wt (N,K) bf16 -------------
__global__ void trans_cast(const float* __restrict__ in, u16* __restrict__ out, int K, int N) {
  __shared__ float tile[32][33];
  int kt = blockIdx.y * 32, nt = blockIdx.x * 32;
  int x = threadIdx.x, y = threadIdx.y;   // (32,8)
  #pragma unroll
  for (int j = 0; j < 32; j += 8)
    tile[y + j][x] = in[(size_t)(kt + y + j) * N + nt + x];
  __syncthreads();
  #pragma unroll
  for (int j = 0; j < 32; j += 8)
    out[(size_t)(nt + y + j) * K + kt + x] = f2bf(tile[x][y + j]);
}

// ---------------- GEMM: A(M,K) bf16 @ Bt(N,K) bf16 -> C(M,N) ----------------
// m97 structure: 128x128 tile, BK=64, 4 waves (2x2), global_load_lds staging.
template <bool OUT_BF16>
__global__ __launch_bounds__(256) void gemm_bt(const u16* __restrict__ A,
                                               const u16* __restrict__ Bt,
                                               void* __restrict__ Cv,
                                               int M, int N, int K) {
  __shared__ u16 As[128 * 64];
  __shared__ u16 Bs[128 * 64];
  const int tid = threadIdx.x;
  const int lane = tid & 63;
  const int wave = tid >> 6;
  const int wr = wave >> 1, wc = wave & 1;
  const int bm = blockIdx.y * 128, bn = blockIdx.x * 128;
  const int ln = lane & 15, gr = lane >> 4;
  f32x4 acc[4][4] = {};
  const u16* Ag = A + (size_t)(bm + (tid >> 3)) * K + (tid & 7) * 8;
  const u16* Bg = Bt + (size_t)(bn + (tid >> 3)) * K + (tid & 7) * 8;
  for (int k0 = 0; k0 < K; k0 += 64) {
    #pragma unroll
    for (int c = 0; c < 4; ++c) {
      gload16(Ag + (size_t)(c * 32) * K + k0, &As[c * 2048 + tid * 8]);
      gload16(Bg + (size_t)(c * 32) * K + k0, &Bs[c * 2048 + tid * 8]);
    }
    __syncthreads();
    #pragma unroll
    for (int ks = 0; ks < 2; ++ks) {
      bf16x8 af[4], bfr[4];
      #pragma unroll
      for (int m = 0; m < 4; ++m)
        af[m] = *(const bf16x8*)&As[(wr * 64 + m * 16 + ln) * 64 + ks * 32 + gr * 8];
      #pragma unroll
      for (int n = 0; n < 4; ++n)
        bfr[n] = *(const bf16x8*)&Bs[(wc * 64 + n * 16 + ln) * 64 + ks * 32 + gr * 8];
      #pragma unroll
      for (int m = 0; m < 4; ++m)
        #pragma unroll
        for (int n = 0; n < 4; ++n)
          acc[m][n] = __builtin_amdgcn_mfma_f32_16x16x32_bf16(af[m], bfr[n], acc[m][n], 0, 0, 0);
    }
    __syncthreads();
  }
  #pragma unroll
  for (int m = 0; m < 4; ++m) {
    #pragma unroll
    for (int j = 0; j < 4; ++j) {
      int r = bm + wr * 64 + m * 16 + gr * 4 + j;
      #pragma unroll
      for (int n = 0; n < 4; ++n) {
        int c = bn + wc * 64 + n * 16 + ln;
        if (OUT_BF16) ((u16*)Cv)[(size_t)r * N + c] = f2bf(acc[m][n][j]);
        else          ((float*)Cv)[(size_t)r * N + c] = acc[m][n][j];
      }
    }
  }
}

// ---- RoPE + transpose: qkv rows (B*T, 11264) cols col_off.. -> (B,NHh,T,128) bf16 ----
__global__ void rope_kernel(const u16* __restrict__ in, u16* __restrict__ out,
                            const float* __restrict__ cosp, const float* __restrict__ sinp,
                            int NHh, int col_off) {
  int idx = blockIdx.x * 256 + threadIdx.x;   // ((b*NHh+h)*1024 + t)*64 + d
  int d = idx & 63;
  int t = (idx >> 6) & 1023;
  int h = (idx >> 16) % NHh;
  int b = (idx >> 16) / NHh;
  size_t src = (size_t)(b * 1024 + t) * 11264 + col_off + h * 128;
  float x1 = bf2f(in[src + d]);
  float x2 = bf2f(in[src + 64 + d]);
  float c = cosp[t * 64 + d], s = sinp[t * 64 + d];
  size_t dst = ((size_t)(b * NHh + h) * 1024 + t) * 128;
  out[dst + d] = f2bf(x1 * c - x2 * s);
  out[dst + 64 + d] = f2bf(x2 * c + x1 * s);
}

// ---- V transpose: qkv cols 10240.. (B,T,Hk*128) -> vt (B,Hk,128,T) bf16 ----
__global__ void vtrans_kernel(const u16* __restrict__ qkv, u16* __restrict__ vt) {
  __shared__ u16 tile[32][34];
  int bh = blockIdx.z;               // b*8 + hk
  int t0 = blockIdx.x * 32, d0 = blockIdx.y * 32;
  int b = bh >> 3, hk = bh & 7;
  int x = threadIdx.x, y = threadIdx.y;   // (32,8)
  #pragma unroll
  for (int j = 0; j < 32; j += 8)
    tile[y + j][x] = qkv[(size_t)(b * 1024 + t0 + y + j) * 11264 + 10240 + hk * 128 + d0 + x];
  __syncthreads();
  #pragma unroll
  for (int j = 0; j < 32; j += 8)
    vt[((size_t)bh * 128 + d0 + y + j) * 1024 + t0 + x] = tile[x][y + j];
}

// ---------------- lambda per head ----------------
__global__ void lam_kernel(const float* __restrict__ lq1, const float* __restrict__ lk1,
                           const float* __restrict__ lq2, const float* __restrict__ lk2,
                           float* __restrict__ lam) {
  int h = blockIdx.x, l = threadIdx.x;   // 64 threads
  float p1 = lq1[h * 128 + l] * lk1[h * 128 + l] + lq1[h * 128 + 64 + l] * lk1[h * 128 + 64 + l];
  float p2 = lq2[h * 128 + l] * lk2[h * 128 + l] + lq2[h * 128 + 64 + l] * lk2[h * 128 + 64 + l];
  #pragma unroll
  for (int m = 32; m >= 1; m >>= 1) { p1 += __shfl_xor(p1, m); p2 += __shfl_xor(p2, m); }
  if (l == 0) lam[h] = expf(p1) - expf(p2) + LAMBDA_INIT_F;
}

// ---------------- fused dual flash attention + diff + RMS subln ----------------
__device__ __forceinline__ void attn_step(const u16* __restrict__ ks, u16* __restrict__ psw,
                                          const u16* __restrict__ vsd, const bf16x8* qf,
                                          f32x4* acc, float* m, float* l,
                                          int kt, int qrow0, int ln, int gr) {
  f32x4 st[2];
  #pragma unroll
  for (int ct = 0; ct < 2; ++ct) {
    st[ct] = (f32x4){0.f, 0.f, 0.f, 0.f};
    #pragma unroll
    for (int ds = 0; ds < 4; ++ds) {
      bf16x8 kf = *(const bf16x8*)&ks[(ct * 16 + ln) * 136 + ds * 32 + gr * 8];
      st[ct] = __builtin_amdgcn_mfma_f32_16x16x32_bf16(qf[ds], kf, st[ct], 0, 0, 0);
    }
  }
  float scl[4];
  #pragma unroll
  for (int j = 0; j < 4; ++j) {
    int row = qrow0 + gr * 4 + j;
    float v0 = st[0][j] * SCALE_F, v1 = st[1][j] * SCALE_F;
    if (kt * 32 + ln > row)      v0 = -1e30f;
    if (kt * 32 + 16 + ln > row) v1 = -1e30f;
    float mx = fmaxf(v0, v1);
    mx = fmaxf(mx, __shfl_xor(mx, 1));
    mx = fmaxf(mx, __shfl_xor(mx, 2));
    mx = fmaxf(mx, __shfl_xor(mx, 4));
    mx = fmaxf(mx, __shfl_xor(mx, 8));
    float mn = fmaxf(m[j], mx);
    float p0 = __expf(v0 - mn);
    float p1 = __expf(v1 - mn);
    u16 b0 = f2bf(p0), b1 = f2bf(p1);
    psw[(gr * 4 + j) * 40 + ln] = b0;
    psw[(gr * 4 + j) * 40 + 16 + ln] = b1;
    float ts = bf2f(b0) + bf2f(b1);   // sum the values PV will actually use
    ts += __shfl_xor(ts, 1);
    ts += __shfl_xor(ts, 2);
    ts += __shfl_xor(ts, 4);
    ts += __shfl_xor(ts, 8);
    float sc = __expf(m[j] - mn);
    l[j] = l[j] * sc + ts;
    m[j] = mn;
    scl[j] = sc;
  }
  #pragma unroll
  for (int dt = 0; dt < 8; ++dt)
    #pragma unroll
    for (int j = 0; j < 4; ++j) acc[dt][j] *= scl[j];
  bf16x8 pf = *(const bf16x8*)&psw[ln * 40 + gr * 8];
  #pragma unroll
  for (int dt = 0; dt < 8; ++dt) {
    bf16x8 vf = *(const bf16x8*)&vsd[(dt * 16 + ln) * 40 + gr * 8];
    acc[dt] = __builtin_amdgcn_mfma_f32_16x16x32_bf16(pf, vf, acc[dt], 0, 0, 0);
  }
}

__global__ __launch_bounds__(256) void attn_kernel(const u16* __restrict__ qr,   // (B,64,T,128)
                                                   const u16* __restrict__ kr,   // (B,16,T,128)
                                                   const u16* __restrict__ vt,   // (B,8,128,T)
                                                   const float* __restrict__ lam,
                                                   const float* __restrict__ slw,
                                                   u16* __restrict__ attno) {    // (B*T, 4096)
  __shared__ u16 k1s[32 * 136];
  __shared__ u16 k2s[32 * 136];
  __shared__ u16 vs[128 * 40];
  __shared__ u16 ps[4][16 * 40];
  const int qt = blockIdx.x, h = blockIdx.y, b = blockIdx.z;
  const int tid = threadIdx.x, lane = tid & 63, w = tid >> 6;
  const int ln = lane & 15, gr = lane >> 4;
  const int hk = h >> 2;
  const int qrow0 = qt * 64 + w * 16;
  u16* psw = ps[w];

  bf16x8 q1f[4], q2f[4];
  {
    const u16* q1p = qr + ((size_t)(b * 64 + h) * 1024 + qrow0 + ln) * 128 + gr * 8;
    const u16* q2p = qr + ((size_t)(b * 64 + 32 + h) * 1024 + qrow0 + ln) * 128 + gr * 8;
    #pragma unroll
    for (int ds = 0; ds < 4; ++ds) {
      q1f[ds] = *(const bf16x8*)(q1p + ds * 32);
      q2f[ds] = *(const bf16x8*)(q2p + ds * 32);
    }
  }
  f32x4 acc1[8] = {}, acc2[8] = {};
  float m1[4], m2[4], l1[4], l2[4];
  #pragma unroll
  for (int j = 0; j < 4; ++j) { m1[j] = m2[j] = -1e30f; l1[j] = l2[j] = 0.f; }

  const u16* k1g = kr + (size_t)(b * 16 + hk) * 1024 * 128;
  const u16* k2g = kr + (size_t)(b * 16 + 8 + hk) * 1024 * 128;
  const u16* vg = vt + (size_t)(b * 8 + hk) * 128 * 1024;
  const int nkt = 2 * qt + 2;

  for (int kt = 0; kt < nkt; ++kt) {
    #pragma unroll
    for (int c = 0; c < 2; ++c) {
      int row = c * 16 + (tid >> 4);
      int ch = tid & 15;
      *(bf16x8*)&k1s[row * 136 + ch * 8] = *(const bf16x8*)&k1g[(size_t)(kt * 32 + row) * 128 + ch * 8];
      *(bf16x8*)&k2s[row * 136 + ch * 8] = *(const bf16x8*)&k2g[(size_t)(kt * 32 + row) * 128 + ch * 8];
      int dr = c * 64 + (tid >> 2);
      int ch2 = tid & 3;
      *(bf16x8*)&vs[dr * 40 + ch2 * 8] = *(const bf16x8*)&vg[(size_t)dr * 1024 + kt * 32 + ch2 * 8];
    }
    __syncthreads();
    attn_step(k1s, psw, vs, q1f, acc1, m1, l1, kt, qrow0, ln, gr);
    attn_step(k2s, psw, vs, q2f, acc2, m2, l2, kt, qrow0, ln, gr);
    __syncthreads();
  }

  // epilogue: o1 - lam*o2, RMS over D=128, * subln_w, -> bf16
  float lamv = lam[h];
  float ssq[4] = {0.f, 0.f, 0.f, 0.f};
  float inv1[4], inv2[4];
  #pragma unroll
  for (int j = 0; j < 4; ++j) { inv1[j] = 1.f / l1[j]; inv2[j] = 1.f / l2[j]; }
  #pragma unroll
  for (int dt = 0; dt < 8; ++dt)
    #pragma unroll
    for (int j = 0; j < 4; ++j) {
      float d = acc1[dt][j] * inv1[j] - lamv * (acc2[dt][j] * inv2[j]);
      acc1[dt][j] = d;
      ssq[j] += d * d;
    }
  #pragma unroll
  for (int j = 0; j < 4; ++j) {
    float s = ssq[j];
    s += __shfl_xor(s, 1);
    s += __shfl_xor(s, 2);
    s += __shfl_xor(s, 4);
    s += __shfl_xor(s, 8);
    ssq[j] = rsqrtf(s * (1.0f / 128.0f) + 1e-6f);
  }
  #pragma unroll
  for (int dt = 0; dt < 8; ++dt) {
    float wgt = slw[dt * 16 + ln];
    #pragma unroll
    for (int j = 0; j < 4; ++j) {
      int row = qrow0 + gr * 4 + j;
      attno[(size_t)(b * 1024 + row) * 4096 + h * 128 + dt * 16 + ln] = f2bf(acc1[dt][j] * ssq[j] * wgt);
    }
  }
}

extern "C" void kernel_launch(void* const* d_in, const int* in_sizes, int n_in,
                              void* d_out, int out_size, void* d_ws, size_t ws_size,
                              hipStream_t stream) {
  (void)in_sizes; (void)n_in; (void)out_size; (void)ws_size;
  const float* x    = (const float*)d_in[0];
  const float* cosp = (const float*)d_in[1];
  const float* sinp = (const float*)d_in[2];
  const float* wq   = (const float*)d_in[3];
  const float* wk   = (const float*)d_in[4];
  const float* wv   = (const float*)d_in[5];
  const float* wo   = (const float*)d_in[6];
  const float* lq1  = (const float*)d_in[7];
  const float* lk1  = (const float*)d_in[8];
  const float* lq2  = (const float*)d_in[9];
  const float* lk2  = (const float*)d_in[10];
  const float* slw  = (const float*)d_in[11];
  float* out = (float*)d_out;
  char* ws = (char*)d_ws;

  // workspace layout (overlays exploit lifetimes; peak ~155 MB)
  u16* xb    = (u16*)(ws);                       // 16.78 MB   [cast -> gemm1]
  u16* wqkvt = (u16*)(ws + 16777216);            // 92.27 MB   [trans -> gemm1]
  u16* qr    = (u16*)(ws + 16777216);            //   overlay: 33.55 MB [rope -> attn]
  u16* kr    = (u16*)(ws + 50331648);            //   overlay:  8.39 MB
  u16* vtp   = (u16*)(ws + 58720256);            //   overlay:  4.19 MB
  u16* attno = (u16*)(ws + 62914560);            //   overlay: 16.78 MB [attn -> gemm2]
  u16* qkv   = (u16*)(ws + 109051904);           // 46.14 MB   [gemm1 -> rope/vtrans]
  u16* wot   = (u16*)(ws + 109051904);           //   overlay: 33.55 MB [trans -> gemm2]
  float* lam = (float*)(ws + 155189248);

  // 1) casts + weight transposes (wq|wk|wv fused into one (11264,4096) B^T)
  cast_f32_bf16<<<8192, 256, 0, stream>>>((const float4*)x, (uint2*)xb, 2097152);
  trans_cast<<<dim3(256, 128), dim3(32, 8), 0, stream>>>(wq, wqkvt, 4096, 8192);
  trans_cast<<<dim3(64, 128),  dim3(32, 8), 0, stream>>>(wk, wqkvt + (size_t)8192 * 4096, 4096, 2048);
  trans_cast<<<dim3(32, 128),  dim3(32, 8), 0, stream>>>(wv, wqkvt + (size_t)10240 * 4096, 4096, 1024);
  // 2) fused QKV projection: (2048,4096) @ (11264,4096)^T -> (2048,11264) bf16
  gemm_bt<true><<<dim3(88, 16), 256, 0, stream>>>(xb, wqkvt, (void*)qkv, 2048, 11264, 4096);
  // 3) RoPE + head-major transposes (qkv buffer consumed; wqkvt region reused)
  rope_kernel<<<32768, 256, 0, stream>>>(qkv, qr, cosp, sinp, 64, 0);
  rope_kernel<<<8192, 256, 0, stream>>>(qkv, kr, cosp, sinp, 16, 8192);
  vtrans_kernel<<<dim3(32, 4, 16), dim3(32, 8), 0, stream>>>(qkv, vtp);
  // 4) wo transpose (into dead qkv region), lambda
  trans_cast<<<dim3(128, 128), dim3(32, 8), 0, stream>>>(wo, wot, 4096, 4096);
  lam_kernel<<<32, 64, 0, stream>>>(lq1, lk1, lq2, lk2, lam);
  // 5) dual causal flash attention + diff + RMS subln -> (2048,4096) bf16
  attn_kernel<<<dim3(16, 32, 2), 256, 0, stream>>>(qr, kr, vtp, lam, slw, attno);
  // 6) output projection -> f32
  gemm_bt<false><<<dim3(32, 16), 256, 0, stream>>>(attno, wot, (void*)out, 2048, 4096, 4096);
}

// Round 2
// 615.411 us; speedup vs baseline: 1.1457x; 1.1457x over previous
//
#include <hip/hip_runtime.h>
#include <hip/hip_bf16.h>
#include <stdint.h>

typedef unsigned short u16;
typedef unsigned int u32;
typedef short bf16x8 __attribute__((ext_vector_type(8)));
typedef float f32x4 __attribute__((ext_vector_type(4)));

#define SCALE_F 0.088388347648318447f   // 1/sqrt(128)
#define LAMBDA_INIT_F 0.2f
// B=2, T=1024, DIM=4096, H=32, Hk=8, D=128, NREP=4

__device__ __forceinline__ u16 f2bf(float f) {
  union { float f; u32 u; } v; v.f = f;
  u32 r = v.u + 0x7fffu + ((v.u >> 16) & 1u);   // RNE
  return (u16)(r >> 16);
}
__device__ __forceinline__ float bf2f(u16 u) {
  union { u32 u; float f; } v; v.u = ((u32)u) << 16;
  return v.f;
}

typedef __attribute__((address_space(1))) void gvoid_t;
typedef __attribute__((address_space(3))) void lvoid_t;
__device__ __forceinline__ void gload16(const void* g, void* l) {
  __builtin_amdgcn_global_load_lds((gvoid_t*)g, (lvoid_t*)l, 16, 0, 0);
}

// ---------------- elementwise cast f32 -> bf16 (vectorized) ----------------
__global__ void cast_f32_bf16(const float4* __restrict__ in, uint2* __restrict__ out, int n4) {
  int i = blockIdx.x * 256 + threadIdx.x;
  if (i >= n4) return;
  float4 v = in[i];
  uint2 o;
  o.x = (u32)f2bf(v.x) | ((u32)f2bf(v.y) << 16);
  o.y = (u32)f2bf(v.z) | ((u32)f2bf(v.w) << 16);
  out[i] = o;
}

// ------------- transpose+cast: w (K,N) f32  ->  wt (N,K) bf16 -------------
__global__ void trans_cast(const float* __restrict__ in, u16* __restrict__ out, int K, int N) {
  __shared__ float tile[32][33];
  int kt = blockIdx.y * 32, nt = blockIdx.x * 32;
  int x = threadIdx.x, y = threadIdx.y;   // (32,8)
  #pragma unroll
  for (int j = 0; j < 32; j += 8)
    tile[y + j][x] = in[(size_t)(kt + y + j) * N + nt + x];
  __syncthreads();
  #pragma unroll
  for (int j = 0; j < 32; j += 8)
    out[(size_t)(nt + y + j) * K + kt + x] = f2bf(tile[x][y + j]);
}

// ---------------- GEMM: A(M,K) bf16 @ Bt(N,K) bf16 -> C(M,N) ----------------
// m97 structure + T2 XOR swizzle: 128x128 tile, BK=64, 4 waves (2x2),
// global_load_lds staging with pre-swizzled SOURCE (rule 21: linear LDS dest,
// swizzled global src chunk, matching XOR on the ds_read address).
template <bool OUT_BF16>
__global__ __launch_bounds__(256) void gemm_bt(const u16* __restrict__ A,
                                               const u16* __restrict__ Bt,
                                               void* __restrict__ Cv,
                                               int M, int N, int K) {
  __shared__ u16 As[128 * 64];
  __shared__ u16 Bs[128 * 64];
  const int tid = threadIdx.x;
  const int lane = tid & 63;
  const int wave = tid >> 6;
  const int wr = wave >> 1, wc = wave & 1;
  const int bm = blockIdx.y * 128, bn = blockIdx.x * 128;
  const int ln = lane & 15, gr = lane >> 4;
  f32x4 acc[4][4] = {};
  // staging: thread tid -> LDS linear slot (row=tid>>3, chunk=tid&7);
  // source chunk is XOR-swizzled by row&7 so the read-side XOR recovers it.
  const int srow = tid >> 3;
  const int schunk = (tid & 7) ^ (srow & 7);
  const u16* Ag = A + (size_t)(bm + srow) * K + schunk * 8;
  const u16* Bg = Bt + (size_t)(bn + srow) * K + schunk * 8;
  for (int k0 = 0; k0 < K; k0 += 64) {
    #pragma unroll
    for (int c = 0; c < 4; ++c) {
      gload16(Ag + (size_t)(c * 32) * K + k0, &As[c * 2048 + tid * 8]);
      gload16(Bg + (size_t)(c * 32) * K + k0, &Bs[c * 2048 + tid * 8]);
    }
    __syncthreads();
    #pragma unroll
    for (int ks = 0; ks < 2; ++ks) {
      bf16x8 af[4], bfr[4];
      #pragma unroll
      for (int m = 0; m < 4; ++m)
        af[m] = *(const bf16x8*)&As[(wr * 64 + m * 16 + ln) * 64 + (((ks * 4 + gr) ^ (ln & 7))) * 8];
      #pragma unroll
      for (int n = 0; n < 4; ++n)
        bfr[n] = *(const bf16x8*)&Bs[(wc * 64 + n * 16 + ln) * 64 + (((ks * 4 + gr) ^ (ln & 7))) * 8];
      #pragma unroll
      for (int m = 0; m < 4; ++m)
        #pragma unroll
        for (int n = 0; n < 4; ++n)
          acc[m][n] = __builtin_amdgcn_mfma_f32_16x16x32_bf16(af[m], bfr[n], acc[m][n], 0, 0, 0);
    }
    __syncthreads();
  }
  #pragma unroll
  for (int m = 0; m < 4; ++m) {
    #pragma unroll
    for (int j = 0; j < 4; ++j) {
      int r = bm + wr * 64 + m * 16 + gr * 4 + j;
      #pragma unroll
      for (int n = 0; n < 4; ++n) {
        int c = bn + wc * 64 + n * 16 + ln;
        if (OUT_BF16) ((u16*)Cv)[(size_t)r * N + c] = f2bf(acc[m][n][j]);
        else          ((float*)Cv)[(size_t)r * N + c] = acc[m][n][j];
      }
    }
  }
}

// ---- RoPE + transpose: qkv rows (B*T, 11264) cols col_off.. -> (B,NHh,T,128) bf16 ----
__global__ void rope_kernel(const u16* __restrict__ in, u16* __restrict__ out,
                            const float* __restrict__ cosp, const float* __restrict__ sinp,
                            int NHh, int col_off) {
  int idx = blockIdx.x * 256 + threadIdx.x;   // ((b*NHh+h)*1024 + t)*64 + d
  int d = idx & 63;
  int t = (idx >> 6) & 1023;
  int h = (idx >> 16) % NHh;
  int b = (idx >> 16) / NHh;
  size_t src = (size_t)(b * 1024 + t) * 11264 + col_off + h * 128;
  float x1 = bf2f(in[src + d]);
  float x2 = bf2f(in[src + 64 + d]);
  float c = cosp[t * 64 + d], s = sinp[t * 64 + d];
  size_t dst = ((size_t)(b * NHh + h) * 1024 + t) * 128;
  out[dst + d] = f2bf(x1 * c - x2 * s);
  out[dst + 64 + d] = f2bf(x2 * c + x1 * s);
}

// ---- V transpose: qkv cols 10240.. (B,T,Hk*128) -> vt (B,Hk,128,T) bf16 ----
__global__ void vtrans_kernel(const u16* __restrict__ qkv, u16* __restrict__ vt) {
  __shared__ u16 tile[32][34];
  int bh = blockIdx.z;               // b*8 + hk
  int t0 = blockIdx.x * 32, d0 = blockIdx.y * 32;
  int b = bh >> 3, hk = bh & 7;
  int x = threadIdx.x, y = threadIdx.y;   // (32,8)
  #pragma unroll
  for (int j = 0; j < 32; j += 8)
    tile[y + j][x] = qkv[(size_t)(b * 1024 + t0 + y + j) * 11264 + 10240 + hk * 128 + d0 + x];
  __syncthreads();
  #pragma unroll
  for (int j = 0; j < 32; j += 8)
    vt[((size_t)bh * 128 + d0 + y + j) * 1024 + t0 + x] = tile[x][y + j];
}

// ---------------- lambda per head ----------------
__global__ void lam_kernel(const float* __restrict__ lq1, const float* __restrict__ lk1,
                           const float* __restrict__ lq2, const float* __restrict__ lk2,
                           float* __restrict__ lam) {
  int h = blockIdx.x, l = threadIdx.x;   // 64 threads
  float p1 = lq1[h * 128 + l] * lk1[h * 128 + l] + lq1[h * 128 + 64 + l] * lk1[h * 128 + 64 + l];
  float p2 = lq2[h * 128 + l] * lk2[h * 128 + l] + lq2[h * 128 + 64 + l] * lk2[h * 128 + 64 + l];
  #pragma unroll
  for (int m = 32; m >= 1; m >>= 1) { p1 += __shfl_xor(p1, m); p2 += __shfl_xor(p2, m); }
  if (l == 0) lam[h] = expf(p1) - expf(p2) + LAMBDA_INIT_F;
}

// ---------------- fused dual flash attention + diff + RMS subln ----------------
__device__ __forceinline__ void attn_step(const u16* __restrict__ ks, u16* __restrict__ psw,
                                          const u16* __restrict__ vsd, const bf16x8* qf,
                                          f32x4* acc, float* m, float* l,
                                          int kt, int qrow0, int ln, int gr) {
  f32x4 st[2];
  #pragma unroll
  for (int ct = 0; ct < 2; ++ct) {
    st[ct] = (f32x4){0.f, 0.f, 0.f, 0.f};
    #pragma unroll
    for (int ds = 0; ds < 4; ++ds) {
      bf16x8 kf = *(const bf16x8*)&ks[(ct * 16 + ln) * 136 + ds * 32 + gr * 8];
      st[ct] = __builtin_amdgcn_mfma_f32_16x16x32_bf16(qf[ds], kf, st[ct], 0, 0, 0);
    }
  }
  float scl[4];
  #pragma unroll
  for (int j = 0; j < 4; ++j) {
    int row = qrow0 + gr * 4 + j;
    float v0 = st[0][j] * SCALE_F, v1 = st[1][j] * SCALE_F;
    if (kt * 32 + ln > row)      v0 = -1e30f;
    if (kt * 32 + 16 + ln > row) v1 = -1e30f;
    float mx = fmaxf(v0, v1);
    mx = fmaxf(mx, __shfl_xor(mx, 1));
    mx = fmaxf(mx, __shfl_xor(mx, 2));
    mx = fmaxf(mx, __shfl_xor(mx, 4));
    mx = fmaxf(mx, __shfl_xor(mx, 8));
    float mn = fmaxf(m[j], mx);
    float p0 = __expf(v0 - mn);
    float p1 = __expf(v1 - mn);
    u16 b0 = f2bf(p0), b1 = f2bf(p1);
    psw[(gr * 4 + j) * 40 + ln] = b0;
    psw[(gr * 4 + j) * 40 + 16 + ln] = b1;
    float ts = bf2f(b0) + bf2f(b1);   // sum the values PV will actually use
    ts += __shfl_xor(ts, 1);
    ts += __shfl_xor(ts, 2);
    ts += __shfl_xor(ts, 4);
    ts += __shfl_xor(ts, 8);
    float sc = __expf(m[j] - mn);
    l[j] = l[j] * sc + ts;
    m[j] = mn;
    scl[j] = sc;
  }
  #pragma unroll
  for (int dt = 0; dt < 8; ++dt)
    #pragma unroll
    for (int j = 0; j < 4; ++j) acc[dt][j] *= scl[j];
  bf16x8 pf = *(const bf16x8*)&psw[ln * 40 + gr * 8];
  #pragma unroll
  for (int dt = 0; dt < 8; ++dt) {
    bf16x8 vf = *(const bf16x8*)&vsd[(dt * 16 + ln) * 40 + gr * 8];
    acc[dt] = __builtin_amdgcn_mfma_f32_16x16x32_bf16(pf, vf, acc[dt], 0, 0, 0);
  }
}

__global__ __launch_bounds__(256) void attn_kernel(const u16* __restrict__ qr,   // (B,64,T,128)
                                                   const u16* __restrict__ kr,   // (B,16,T,128)
                                                   const u16* __restrict__ vt,   // (B,8,128,T)
                                                   const float* __restrict__ lam,
                                                   const float* __restrict__ slw,
                                                   u16* __restrict__ attno) {    // (B*T, 4096)
  __shared__ u16 k1s[32 * 136];
  __shared__ u16 k2s[32 * 136];
  __shared__ u16 vs[128 * 40];
  __shared__ u16 ps[4][16 * 40];
  const int qt = blockIdx.x, h = blockIdx.y, b = blockIdx.z;
  const int tid = threadIdx.x, lane = tid & 63, w = tid >> 6;
  const int ln = lane & 15, gr = lane >> 4;
  const int hk = h >> 2;
  const int qrow0 = qt * 64 + w * 16;
  u16* psw = ps[w];

  bf16x8 q1f[4], q2f[4];
  {
    const u16* q1p = qr + ((size_t)(b * 64 + h) * 1024 + qrow0 + ln) * 128 + gr * 8;
    const u16* q2p = qr + ((size_t)(b * 64 + 32 + h) * 1024 + qrow0 + ln) * 128 + gr * 8;
    #pragma unroll
    for (int ds = 0; ds < 4; ++ds) {
      q1f[ds] = *(const bf16x8*)(q1p + ds * 32);
      q2f[ds] = *(const bf16x8*)(q2p + ds * 32);
    }
  }
  f32x4 acc1[8] = {}, acc2[8] = {};
  float m1[4], m2[4], l1[4], l2[4];
  #pragma unroll
  for (int j = 0; j < 4; ++j) { m1[j] = m2[j] = -1e30f; l1[j] = l2[j] = 0.f; }

  const u16* k1g = kr + (size_t)(b * 16 + hk) * 1024 * 128;
  const u16* k2g = kr + (size_t)(b * 16 + 8 + hk) * 1024 * 128;
  const u16* vg = vt + (size_t)(b * 8 + hk) * 128 * 1024;
  const int nkt = 2 * qt + 2;

  for (int kt = 0; kt < nkt; ++kt) {
    #pragma unroll
    for (int c = 0; c < 2; ++c) {
      int row = c * 16 + (tid >> 4);
      int ch = tid & 15;
      *(bf16x8*)&k1s[row * 136 + ch * 8] = *(const bf16x8*)&k1g[(size_t)(kt * 32 + row) * 128 + ch * 8];
      *(bf16x8*)&k2s[row * 136 + ch * 8] = *(const bf16x8*)&k2g[(size_t)(kt * 32 + row) * 128 + ch * 8];
      int dr = c * 64 + (tid >> 2);
      int ch2 = tid & 3;
      *(bf16x8*)&vs[dr * 40 + ch2 * 8] = *(const bf16x8*)&vg[(size_t)dr * 1024 + kt * 32 + ch2 * 8];
    }
    __syncthreads();
    attn_step(k1s, psw, vs, q1f, acc1, m1, l1, kt, qrow0, ln, gr);
    attn_step(k2s, psw, vs, q2f, acc2, m2, l2, kt, qrow0, ln, gr);
    __syncthreads();
  }

  // epilogue: o1 - lam*o2, RMS over D=128, * subln_w, -> bf16
  float lamv = lam[h];
  float ssq[4] = {0.f, 0.f, 0.f, 0.f};
  float inv1[4], inv2[4];
  #pragma unroll
  for (int j = 0; j < 4; ++j) { inv1[j] = 1.f / l1[j]; inv2[j] = 1.f / l2[j]; }
  #pragma unroll
  for (int dt = 0; dt < 8; ++dt)
    #pragma unroll
    for (int j = 0; j < 4; ++j) {
      float d = acc1[dt][j] * inv1[j] - lamv * (acc2[dt][j] * inv2[j]);
      acc1[dt][j] = d;
      ssq[j] += d * d;
    }
  #pragma unroll
  for (int j = 0; j < 4; ++j) {
    float s = ssq[j];
    s += __shfl_xor(s, 1);
    s += __shfl_xor(s, 2);
    s += __shfl_xor(s, 4);
    s += __shfl_xor(s, 8);
    ssq[j] = rsqrtf(s * (1.0f / 128.0f) + 1e-6f);
  }
  #pragma unroll
  for (int dt = 0; dt < 8; ++dt) {
    float wgt = slw[dt * 16 + ln];
    #pragma unroll
    for (int j = 0; j < 4; ++j) {
      int row = qrow0 + gr * 4 + j;
      attno[(size_t)(b * 1024 + row) * 4096 + h * 128 + dt * 16 + ln] = f2bf(acc1[dt][j] * ssq[j] * wgt);
    }
  }
}

extern "C" void kernel_launch(void* const* d_in, const int* in_sizes, int n_in,
                              void* d_out, int out_size, void* d_ws, size_t ws_size,
                              hipStream_t stream) {
  (void)in_sizes; (void)n_in; (void)out_size; (void)ws_size;
  const float* x    = (const float*)d_in[0];
  const float* cosp = (const float*)d_in[1];
  const float* sinp = (const float*)d_in[2];
  const float* wq   = (const float*)d_in[3];
  const float* wk   = (const float*)d_in[4];
  const float* wv   = (const float*)d_in[5];
  const float* wo   = (const float*)d_in[6];
  const float* lq1  = (const float*)d_in[7];
  const float* lk1  = (const float*)d_in[8];
  const float* lq2  = (const float*)d_in[9];
  const float* lk2  = (const float*)d_in[10];
  const float* slw  = (const float*)d_in[11];
  float* out = (float*)d_out;
  char* ws = (char*)d_ws;

  // workspace layout (overlays exploit lifetimes; peak ~155 MB)
  u16* xb    = (u16*)(ws);                       // 16.78 MB   [cast -> gemm1]
  u16* wqkvt = (u16*)(ws + 16777216);            // 92.27 MB   [trans -> gemm1]
  u16* qr    = (u16*)(ws + 16777216);            //   overlay: 33.55 MB [rope -> attn]
  u16* kr    = (u16*)(ws + 50331648);            //   overlay:  8.39 MB
  u16* vtp   = (u16*)(ws + 58720256);            //   overlay:  4.19 MB
  u16* attno = (u16*)(ws + 62914560);            //   overlay: 16.78 MB [attn -> gemm2]
  u16* qkv   = (u16*)(ws + 109051904);           // 46.14 MB   [gemm1 -> rope/vtrans]
  u16* wot   = (u16*)(ws + 109051904);           //   overlay: 33.55 MB [trans -> gemm2]
  float* lam = (float*)(ws + 155189248);

  // 1) casts + weight transposes (wq|wk|wv fused into one (11264,4096) B^T)
  cast_f32_bf16<<<8192, 256, 0, stream>>>((const float4*)x, (uint2*)xb, 2097152);
  trans_cast<<<dim3(256, 128), dim3(32, 8), 0, stream>>>(wq, wqkvt, 4096, 8192);
  trans_cast<<<dim3(64, 128),  dim3(32, 8), 0, stream>>>(wk, wqkvt + (size_t)8192 * 4096, 4096, 2048);
  trans_cast<<<dim3(32, 128),  dim3(32, 8), 0, stream>>>(wv, wqkvt + (size_t)10240 * 4096, 4096, 1024);
  // 2) fused QKV projection: (2048,4096) @ (11264,4096)^T -> (2048,11264) bf16
  gemm_bt<true><<<dim3(88, 16), 256, 0, stream>>>(xb, wqkvt, (void*)qkv, 2048, 11264, 4096);
  // 3) RoPE + head-major transposes (qkv buffer consumed; wqkvt region reused)
  rope_kernel<<<32768, 256, 0, stream>>>(qkv, qr, cosp, sinp, 64, 0);
  rope_kernel<<<8192, 256, 0, stream>>>(qkv, kr, cosp, sinp, 16, 8192);
  vtrans_kernel<<<dim3(32, 4, 16), dim3(32, 8), 0, stream>>>(qkv, vtp);
  // 4) wo transpose (into dead qkv region), lambda
  trans_cast<<<dim3(128, 128), dim3(32, 8), 0, stream>>>(wo, wot, 4096, 4096);
  lam_kernel<<<32, 64, 0, stream>>>(lq1, lk1, lq2, lk2, lam);
  // 5) dual causal flash attention + diff + RMS subln -> (2048,4096) bf16
  attn_kernel<<<dim3(16, 32, 2), 256, 0, stream>>>(qr, kr, vtp, lam, slw, attno);
  // 6) output projection -> f32
  gemm_bt<false><<<dim3(32, 16), 256, 0, stream>>>(attno, wot, (void*)out, 2048, 4096, 4096);
}